// Round 1
// baseline (238.013 us; speedup 1.0000x reference)
//
#include <hip/hip_runtime.h>

#define NN      131072
#define H       256
#define PPATHS  32768
#define LMAX    16
#define EF      8
#define FF      16
#define KP      288        // padded K: 256 pe + 8 edge + 16 scal + 8 zero
#define TPB     16         // paths per block (fused kernel): 4 paths/wave
#define FS      296        // feat LDS row stride in ushorts (592 B: 16B-aligned)

typedef short v8s __attribute__((ext_vector_type(8)));
typedef float v4f __attribute__((ext_vector_type(4)));

__device__ __forceinline__ unsigned short f2bf(float x) {
    unsigned int u = __float_as_uint(x);
    u += 0x7fffu + ((u >> 16) & 1u);     // round-to-nearest-even
    return (unsigned short)(u >> 16);
}

// blocks [0,288): W1T[n][k] = bf16(W1[orig(k)][n]) (k>=280 -> 0)
// blocks [288,352): cvec[j] = b1[j] + sum_{k<512} concat(src,dst)[k]*W1[k][j]
__global__ __launch_bounds__(256) void prep_kernel(
        const float* __restrict__ node_embs,
        const float* __restrict__ W1,
        const float* __restrict__ b1,
        const int*   __restrict__ si,
        const int*   __restrict__ di,
        unsigned short* __restrict__ W1T,
        float*       __restrict__ cvec) {
    __shared__ float red[256];
    const int b = blockIdx.x;
    if (b < KP) {
        const int k = b, n = threadIdx.x;
        float v = 0.0f;
        if (k < 256)      v = W1[(size_t)(512 + k) * H + n];
        else if (k < 280) v = W1[(size_t)(768 + (k - 256)) * H + n];
        W1T[(size_t)n * KP + k] = f2bf(v);
    } else {
        const int jb = b - KP;             // 0..63
        const int t  = threadIdx.x;
        const int jl = t & 3, kp = t >> 2;
        const int j  = jb * 4 + jl;
        const float* src = node_embs + (size_t)si[0] * H;
        const float* dst = node_embs + (size_t)di[0] * H;
        float c = 0.0f;
        #pragma unroll
        for (int i = 0; i < 8; ++i) {
            int k = kp + i * 64;
            float f = (k < H) ? src[k] : dst[k - H];
            c += f * W1[(size_t)k * H + j];
        }
        red[t] = c;
        __syncthreads();
        for (int s = 128; s >= 4; s >>= 1) {
            if (t < s) red[t] += red[t + s];
            __syncthreads();
        }
        if (t < 4) cvec[jb * 4 + t] = b1[jb * 4 + t] + red[t];
    }
}

// Fused: block = 16 paths, 4 waves. Phase A: each wave gathers 4 paths ->
// LDS bf16 feat tile (half the serial dependent-chain length of the TPB=32
// version; 9.8 KB LDS -> LDS never caps occupancy; launch_bounds(256,6)
// targets 6 waves/SIMD to fill L3 gather latency). Phase B: MFMA GEMM,
// M=16 (one A-frag), wave w owns 64 cols; fused relu/W2/reduce epilogue.
__global__ __launch_bounds__(256, 6) void fused_kernel(
        const float* __restrict__ node_embs,
        const int*   __restrict__ path_nodes,
        const int*   __restrict__ path_lens,
        const float* __restrict__ edge_f,
        const float* __restrict__ scal_f,
        const unsigned short* __restrict__ W1T,
        const float* __restrict__ cvec,
        const float* __restrict__ W2,
        const float* __restrict__ b2,
        float*       __restrict__ out) {
    __shared__ __align__(16) unsigned short feat[TPB * FS];   // 9.25 KB
    __shared__ float qpart[TPB][5];

    const int tid  = threadIdx.x;
    const int wave = tid >> 6, lane = tid & 63;
    const int pb   = blockIdx.x * TPB;

    // cols 256..287: edge, scalar, zero pad (issued first so loads fly early)
    for (int i = tid; i < TPB * 32; i += 256) {
        const int p = i >> 5, s = i & 31;
        float v = 0.0f;
        if (s < EF)           v = edge_f[(size_t)(pb + p) * EF + s];
        else if (s < EF + FF) v = scal_f[(size_t)(pb + p) * FF + (s - EF)];
        feat[p * FS + H + s] = f2bf(v);
    }

    // Phase A: gather + mean, wave w handles paths [4w, 4w+4)
    for (int pi = 0; pi < 4; ++pi) {
        const int p   = wave * 4 + pi;
        const int gp  = pb + p;
        const int len = path_lens[gp];
        const int iv  = path_nodes[(size_t)gp * LMAX + (lane & 15)];

        float4 a0 = make_float4(0, 0, 0, 0), a1 = make_float4(0, 0, 0, 0);
        float4 a2 = make_float4(0, 0, 0, 0), a3 = make_float4(0, 0, 0, 0);
        int l = 0;
        for (; l + 3 < len; l += 4) {
            const int n0 = __shfl(iv, l);
            const int n1 = __shfl(iv, l + 1);
            const int n2 = __shfl(iv, l + 2);
            const int n3 = __shfl(iv, l + 3);
            const float4 v0 = ((const float4*)(node_embs + (size_t)n0 * H))[lane];
            const float4 v1 = ((const float4*)(node_embs + (size_t)n1 * H))[lane];
            const float4 v2 = ((const float4*)(node_embs + (size_t)n2 * H))[lane];
            const float4 v3 = ((const float4*)(node_embs + (size_t)n3 * H))[lane];
            a0.x += v0.x; a0.y += v0.y; a0.z += v0.z; a0.w += v0.w;
            a1.x += v1.x; a1.y += v1.y; a1.z += v1.z; a1.w += v1.w;
            a2.x += v2.x; a2.y += v2.y; a2.z += v2.z; a2.w += v2.w;
            a3.x += v3.x; a3.y += v3.y; a3.z += v3.z; a3.w += v3.w;
        }
        for (; l < len; ++l) {
            const int n0 = __shfl(iv, l);
            const float4 v0 = ((const float4*)(node_embs + (size_t)n0 * H))[lane];
            a0.x += v0.x; a0.y += v0.y; a0.z += v0.z; a0.w += v0.w;
        }
        const float inv = 1.0f / (float)max(len, 1);
        ushort4 r;
        r.x = f2bf((a0.x + a1.x + a2.x + a3.x) * inv);
        r.y = f2bf((a0.y + a1.y + a2.y + a3.y) * inv);
        r.z = f2bf((a0.z + a1.z + a2.z + a3.z) * inv);
        r.w = f2bf((a0.w + a1.w + a2.w + a3.w) * inv);
        *(ushort4*)&feat[p * FS + 4 * lane] = r;     // 8B aligned
    }
    __syncthreads();

    // Phase B: MFMA GEMM, M=16. wave w owns cols n in [64w, 64w+64).
    const int col = lane & 15, quad = lane >> 4;
    const int n0  = wave * 64;

    v4f acc[4];
    float w2v[4];
    #pragma unroll
    for (int nt = 0; nt < 4; ++nt) {
        const float cv = cvec[n0 + nt * 16 + col];
        w2v[nt] = W2[n0 + nt * 16 + col];
        acc[nt] = (v4f){cv, cv, cv, cv};
    }

    // A-frag: lane holds feat[col][k0 + quad*8 + j]  (LDS, 16B contig)
    // B-frag: lane holds W1T [n0 + nt*16 + col][k0 + quad*8 + j]
    const unsigned short* Alds  = feat + col * FS + quad * 8;
    const unsigned short* Bbase = W1T + (size_t)(n0 + col) * KP + quad * 8;

    for (int k0 = 0; k0 < KP; k0 += 32) {
        v8s a, b[4];
        a = *(const v8s*)(Alds + k0);
        #pragma unroll
        for (int nt = 0; nt < 4; ++nt)
            b[nt] = *(const v8s*)(Bbase + (size_t)(nt * 16) * KP + k0);
        #pragma unroll
        for (int nt = 0; nt < 4; ++nt)
            acc[nt] = __builtin_amdgcn_mfma_f32_16x16x32_bf16(
                          a, b[nt], acc[nt], 0, 0, 0);
    }

    // Epilogue: relu * W2, reduce this wave's 64 cols; C/D: col=lane&15, row=quad*4+r
    {
        float s[4];
        #pragma unroll
        for (int r = 0; r < 4; ++r) {
            float v = 0.0f;
            #pragma unroll
            for (int nt = 0; nt < 4; ++nt)
                v += fmaxf(acc[nt][r], 0.0f) * w2v[nt];
            s[r] = v;
        }
        #pragma unroll
        for (int off = 1; off < 16; off <<= 1) {
            #pragma unroll
            for (int r = 0; r < 4; ++r)
                s[r] += __shfl_xor(s[r], off);
        }
        if (col == 0) {
            #pragma unroll
            for (int r = 0; r < 4; ++r)
                qpart[quad * 4 + r][wave] = s[r];
        }
    }
    __syncthreads();

    if (tid < TPB) {
        const float q = qpart[tid][0] + qpart[tid][1] + qpart[tid][2] + qpart[tid][3] + b2[0];
        out[pb + tid] = (path_lens[pb + tid] > 0) ? q : 0.0f;
    }
}

extern "C" void kernel_launch(void* const* d_in, const int* in_sizes, int n_in,
                              void* d_out, int out_size, void* d_ws, size_t ws_size,
                              hipStream_t stream) {
    const float* node_embs  = (const float*)d_in[0];
    const int*   path_nodes = (const int*)d_in[1];
    const int*   path_lens  = (const int*)d_in[2];
    const float* edge_f     = (const float*)d_in[3];
    const float* scal_f     = (const float*)d_in[4];
    const float* W1         = (const float*)d_in[5];
    const float* b1         = (const float*)d_in[6];
    const float* W2         = (const float*)d_in[7];
    const float* b2         = (const float*)d_in[8];
    const int*   si         = (const int*)d_in[9];
    const int*   di         = (const int*)d_in[10];
    float* out = (float*)d_out;

    // workspace: cvec (1 KB) | W1T (147456 B)
    float*          cvec = (float*)d_ws;
    unsigned short* W1T  = (unsigned short*)((char*)d_ws + 1024);

    hipLaunchKernelGGL(prep_kernel, dim3(KP + 64), dim3(256), 0, stream,
                       node_embs, W1, b1, si, di, W1T, cvec);
    hipLaunchKernelGGL(fused_kernel, dim3(PPATHS / TPB), dim3(256), 0, stream,
                       node_embs, path_nodes, path_lens, edge_f, scal_f,
                       W1T, cvec, W2, b2, out);
}